// Round 4
// baseline (727.923 us; speedup 1.0000x reference)
//
#include <hip/hip_runtime.h>
#include <hip/hip_bf16.h>

// Problem constants (from reference)
#define Nn   40000
#define Ee   640000
#define Gg   64
#define INF  128
#define Hh   256
#define OUTF 128

#define NBLK_N 157   // ceil(40000/256)

// ---------------- degree histogram ----------------
__global__ __launch_bounds__(256) void k_count(const int* __restrict__ dst, int* __restrict__ cnt) {
    int e = blockIdx.x * 256 + threadIdx.x;
    if (e < Ee) atomicAdd(&cnt[dst[e]], 1);
}

__global__ __launch_bounds__(256) void k_dis(const int* __restrict__ cnt, float* __restrict__ dis) {
    int i = blockIdx.x * 256 + threadIdx.x;
    if (i < Nn) dis[i] = rsqrtf((float)cnt[i] + 1.0f);
}

// ---------------- two-level exclusive scan: cnt[40000] -> offs[40001] ----------------
__global__ __launch_bounds__(256)
void k_scan1(const int* __restrict__ cnt, int* __restrict__ offs, int* __restrict__ partial) {
    __shared__ int sm[256];
    int i = blockIdx.x * 256 + threadIdx.x;
    int v = (i < Nn) ? cnt[i] : 0;
    sm[threadIdx.x] = v;
    __syncthreads();
#pragma unroll
    for (int d = 1; d < 256; d <<= 1) {
        int t = (threadIdx.x >= d) ? sm[threadIdx.x - d] : 0;
        __syncthreads();
        sm[threadIdx.x] += t;
        __syncthreads();
    }
    if (i < Nn) offs[i] = sm[threadIdx.x] - v;
    if (threadIdx.x == 255) partial[blockIdx.x] = sm[255];
}

__global__ __launch_bounds__(256)
void k_scan2(int* __restrict__ partial) {
    __shared__ int sm[256];
    int v = (threadIdx.x < NBLK_N) ? partial[threadIdx.x] : 0;
    sm[threadIdx.x] = v;
    __syncthreads();
#pragma unroll
    for (int d = 1; d < 256; d <<= 1) {
        int t = (threadIdx.x >= d) ? sm[threadIdx.x - d] : 0;
        __syncthreads();
        sm[threadIdx.x] += t;
        __syncthreads();
    }
    if (threadIdx.x < NBLK_N) partial[threadIdx.x] = sm[threadIdx.x] - v;
}

__global__ __launch_bounds__(256)
void k_scan3(int* __restrict__ offs, const int* __restrict__ partial) {
    int i = blockIdx.x * 256 + threadIdx.x;
    if (i < Nn) offs[i] += partial[blockIdx.x];
    if (i == 0) offs[Nn] = Ee;
}

// ---------------- CSR fill: bucket src ids by dst ----------------
__global__ __launch_bounds__(256)
void k_fill(const int* __restrict__ src, const int* __restrict__ dst,
            const int* __restrict__ offs, int* __restrict__ cursor,
            unsigned short* __restrict__ src_sorted) {
    int e = blockIdx.x * 256 + threadIdx.x;
    if (e >= Ee) return;
    int d = dst[e];
    int pos = offs[d] + atomicAdd(&cursor[d], 1);
    src_sorted[pos] = (unsigned short)src[e];
}

// ---------------- fp32 tiled GEMM: C[M,N] = A[M,K] @ B[K,N] ----------------
// 128x128 tile, 256 threads, 8x8 micro-tile as 4 quadrants of 4x4, BK=16.
// Row-guarded for M not divisible by 128. N%128==0, K%16==0.
__global__ __launch_bounds__(256, 3)
void k_gemm128(const float* __restrict__ A, const float* __restrict__ B,
               float* __restrict__ C, int M, int N, int K) {
    __shared__ float As[16][132];   // transposed A tile
    __shared__ float Bs[16][132];
    const int tid = threadIdx.x;
    const int rowBase = blockIdx.x * 128;
    const int colBase = blockIdx.y * 128;

    // A staging: 128 rows x 16 cols, 2 float4 per thread
    const int ar  = tid >> 2;            // 0..63
    const int akc = (tid & 3) * 4;       // 0,4,8,12
    // B staging: 16 rows x 128 cols, 2 float4 per thread
    const int br = tid >> 5;             // 0..7
    const int bc = (tid & 31) * 4;       // 0..124
    // micro-tile coords (4 quadrants of 4x4)
    const int ty4 = (tid >> 4) * 4;      // 0..60
    const int tx4 = (tid & 15) * 4;      // 0..60

    float acc[8][8] = {};

    for (int k0 = 0; k0 < K; k0 += 16) {
        int r0 = rowBase + ar;       if (r0 >= M) r0 = M - 1;
        int r1 = rowBase + ar + 64;  if (r1 >= M) r1 = M - 1;
        float4 a0 = *(const float4*)&A[(size_t)r0 * K + k0 + akc];
        float4 a1 = *(const float4*)&A[(size_t)r1 * K + k0 + akc];
        float4 b0 = *(const float4*)&B[(size_t)(k0 + br) * N + colBase + bc];
        float4 b1 = *(const float4*)&B[(size_t)(k0 + br + 8) * N + colBase + bc];
        __syncthreads();
        As[akc + 0][ar] = a0.x; As[akc + 1][ar] = a0.y;
        As[akc + 2][ar] = a0.z; As[akc + 3][ar] = a0.w;
        As[akc + 0][ar + 64] = a1.x; As[akc + 1][ar + 64] = a1.y;
        As[akc + 2][ar + 64] = a1.z; As[akc + 3][ar + 64] = a1.w;
        *(float4*)&Bs[br][bc]     = b0;
        *(float4*)&Bs[br + 8][bc] = b1;
        __syncthreads();
#pragma unroll
        for (int kk = 0; kk < 16; ++kk) {
            float a[8], b[8];
            *(float4*)&a[0] = *(const float4*)&As[kk][ty4];
            *(float4*)&a[4] = *(const float4*)&As[kk][ty4 + 64];
            *(float4*)&b[0] = *(const float4*)&Bs[kk][tx4];
            *(float4*)&b[4] = *(const float4*)&Bs[kk][tx4 + 64];
#pragma unroll
            for (int i = 0; i < 8; ++i)
#pragma unroll
                for (int j = 0; j < 8; ++j)
                    acc[i][j] += a[i] * b[j];
        }
    }
#pragma unroll
    for (int i = 0; i < 8; ++i) {
        int r = rowBase + ((i < 4) ? (ty4 + i) : (ty4 + 64 + (i - 4)));
        if (r < M) {
            *(float4*)&C[(size_t)r * N + colBase + tx4] =
                make_float4(acc[i][0], acc[i][1], acc[i][2], acc[i][3]);
            *(float4*)&C[(size_t)r * N + colBase + tx4 + 64] =
                make_float4(acc[i][4], acc[i][5], acc[i][6], acc[i][7]);
        }
    }
}

// ---------------- XCD-sliced CSR gather + self-loop + bias (+ReLU) ----------------
// Feature dim split into SLICES slices of 32 floats (one 128B L2 line per row).
// slice = blockIdx.x % SLICES -> with round-robin block->XCD mapping, each XCD
// touches only ~40000*128B = 5.1 MB of h, nearly L2-resident.
// Each half-wave (32 lanes) handles one dst node's slice.
template <int HH, int SLICES, bool RELU>
__global__ __launch_bounds__(256)
void k_gather_slice(const int* __restrict__ offs, const unsigned short* __restrict__ srcs,
                    const float* __restrict__ dis, const float* __restrict__ h,
                    const float* __restrict__ bias, float* __restrict__ out) {
    int bid = blockIdx.x;
    int slice = bid % SLICES;
    int chunk = bid / SLICES;
    int n = chunk * 8 + (threadIdx.x >> 5);   // 8 nodes per block (half-wave each)
    if (n >= Nn) return;
    int lane = threadIdx.x & 31;
    int col = slice * 32 + lane;
    const float dn = dis[n];
    float acc = 0.0f;
    int b = offs[n], e = offs[n + 1];
    int i = b;
    for (; i + 1 < e; i += 2) {
        int s0 = srcs[i], s1 = srcs[i + 1];
        float w0 = dis[s0] * dn, w1 = dis[s1] * dn;
        acc += w0 * h[(size_t)s0 * HH + col];
        acc += w1 * h[(size_t)s1 * HH + col];
    }
    if (i < e) {
        int s0 = srcs[i];
        acc += dis[s0] * dn * h[(size_t)s0 * HH + col];
    }
    float r = acc + dn * dn * h[(size_t)n * HH + col] + bias[col];
    if (RELU) r = fmaxf(r, 0.0f);
    out[(size_t)n * HH + col] = r;
}

// ---------------- pool phase 1: chunked segment-aware accumulation ----------------
__global__ __launch_bounds__(256)
void k_pool_accum(const float* __restrict__ emb, const int* __restrict__ batch,
                  float* __restrict__ ge_accum) {
    int n0 = blockIdx.x * 64;
    int nend = min(n0 + 64, Nn);
    int sub = threadIdx.x >> 6;
    int col = (threadIdx.x & 63) * 2;
    float ax = 0.0f, ay = 0.0f;
    int cur_g = -1;
    for (int n = n0 + sub; n < nend; n += 4) {
        int g = batch[n];
        if (g != cur_g) {
            if (cur_g >= 0) {
                unsafeAtomicAdd(&ge_accum[cur_g * OUTF + col], ax);
                unsafeAtomicAdd(&ge_accum[cur_g * OUTF + col + 1], ay);
            }
            cur_g = g; ax = 0.0f; ay = 0.0f;
        }
        float2 v = *(const float2*)&emb[(size_t)n * OUTF + col];
        ax += v.x; ay += v.y;
    }
    if (cur_g >= 0) {
        unsafeAtomicAdd(&ge_accum[cur_g * OUTF + col], ax);
        unsafeAtomicAdd(&ge_accum[cur_g * OUTF + col + 1], ay);
    }
}

// ---------------- pool phase 2: divide by segment count ----------------
__global__ __launch_bounds__(256)
void k_pool_div(const float* __restrict__ ge_accum, const int* __restrict__ batch,
                float* __restrict__ ge) {
    int idx = blockIdx.x * 256 + threadIdx.x;
    if (idx >= Gg * OUTF) return;
    int g = idx >> 7;
    int lo = 0, hi = Nn;
    while (lo < hi) { int mid = (lo + hi) >> 1; if (batch[mid] < g) lo = mid + 1; else hi = mid; }
    int start = lo;
    hi = Nn;
    while (lo < hi) { int mid = (lo + hi) >> 1; if (batch[mid] < g + 1) lo = mid + 1; else hi = mid; }
    float cnt = (float)(lo - start);
    ge[idx] = ge_accum[idx] / fmaxf(cnt, 1.0f);
}

// ---------------- logits: ge[64,128] @ W_cls[128,2] + b_cls ----------------
__global__ __launch_bounds__(128)
void k_logits(const float* __restrict__ ge, const float* __restrict__ Wc,
              const float* __restrict__ bc, float* __restrict__ out) {
    int t = threadIdx.x;
    int g = t >> 1, c = t & 1;
    float s = bc[c];
    for (int k = 0; k < 128; ++k) s += ge[g * 128 + k] * Wc[k * 2 + c];
    out[t] = s;
}

extern "C" void kernel_launch(void* const* d_in, const int* in_sizes, int n_in,
                              void* d_out, int out_size, void* d_ws, size_t ws_size,
                              hipStream_t stream) {
    const float* x     = (const float*)d_in[0];
    const int*   ei    = (const int*)d_in[1];
    const int*   batch = (const int*)d_in[2];
    const float* W_in  = (const float*)d_in[3];
    const float* b_in  = (const float*)d_in[4];
    const float* W_mid = (const float*)d_in[5];
    const float* b_mid = (const float*)d_in[6];
    const float* W_out = (const float*)d_in[7];
    const float* b_out = (const float*)d_in[8];
    const float* W_cls = (const float*)d_in[9];
    const float* b_cls = (const float*)d_in[10];

    const int* src = ei;
    const int* dst = ei + Ee;

    // workspace layout (4B units)
    float* ws = (float*)d_ws;
    float* dis     = ws;                           // 0
    int*   cnt     = (int*)(ws + 40000);           // 40000
    int*   offs    = (int*)(ws + 80000);           // 80000..120064
    int*   partial = (int*)(ws + 120064);          // 192
    float* ge_accum = ws + 120256;                 // 8192
    unsigned short* src_sorted = (unsigned short*)(ws + 128448);
    float* bufA = ws + 448448;
    float* bufB = ws + 10688448;
    // end = 20,928,448 floats = 83.7 MB

    float* out    = (float*)d_out;
    float* ge_out = out + (size_t)Nn * OUTF;
    float* lg_out = ge_out + Gg * OUTF;

    const int nBlkE = (Ee + 255) / 256;
    const int gRows = (Nn + 127) / 128;            // 313

    // ---- CSR build ----
    hipMemsetAsync(cnt, 0, Nn * sizeof(int), stream);
    k_count<<<nBlkE, 256, 0, stream>>>(dst, cnt);
    k_dis<<<NBLK_N, 256, 0, stream>>>(cnt, dis);
    k_scan1<<<NBLK_N, 256, 0, stream>>>(cnt, offs, partial);
    k_scan2<<<1, 256, 0, stream>>>(partial);
    k_scan3<<<NBLK_N, 256, 0, stream>>>(offs, partial);
    hipMemsetAsync(cnt, 0, Nn * sizeof(int), stream);
    k_fill<<<nBlkE, 256, 0, stream>>>(src, dst, offs, cnt, src_sorted);

    // ---- layer 1 ----
    k_gemm128<<<dim3(gRows, Hh / 128), 256, 0, stream>>>(x, W_in, bufA, Nn, Hh, INF);
    k_gather_slice<Hh, 8, true><<<(Nn / 8) * 8, 256, 0, stream>>>(offs, src_sorted, dis, bufA, b_in, bufB);

    // ---- layer 2 ----
    k_gemm128<<<dim3(gRows, Hh / 128), 256, 0, stream>>>(bufB, W_mid, bufA, Nn, Hh, Hh);
    k_gather_slice<Hh, 8, true><<<(Nn / 8) * 8, 256, 0, stream>>>(offs, src_sorted, dis, bufA, b_mid, bufB);

    // ---- layer 3 -> node embeddings in d_out ----
    k_gemm128<<<dim3(gRows, OUTF / 128), 256, 0, stream>>>(bufB, W_out, bufA, Nn, OUTF, Hh);
    k_gather_slice<OUTF, 4, false><<<(Nn / 8) * 4, 256, 0, stream>>>(offs, src_sorted, dis, bufA, b_out, out);

    // ---- pooling + classifier ----
    hipMemsetAsync(ge_accum, 0, Gg * OUTF * sizeof(float), stream);
    k_pool_accum<<<(Nn + 63) / 64, 256, 0, stream>>>(out, batch, ge_accum);
    k_pool_div<<<(Gg * OUTF + 255) / 256, 256, 0, stream>>>(ge_accum, batch, ge_out);
    k_logits<<<1, 128, 0, stream>>>(ge_out, W_cls, b_cls, lg_out);
}

// Round 5
// 575.203 us; speedup vs baseline: 1.2655x; 1.2655x over previous
//
#include <hip/hip_runtime.h>
#include <hip/hip_bf16.h>

// Problem constants (from reference)
#define Nn   40000
#define Ee   640000
#define Gg   64
#define INF  128
#define Hh   256
#define OUTF 128

#define NBLK_N 157   // ceil(40000/256)

// ---------------- degree histogram ----------------
__global__ __launch_bounds__(256) void k_count(const int* __restrict__ dst, int* __restrict__ cnt) {
    int e = blockIdx.x * 256 + threadIdx.x;
    if (e < Ee) atomicAdd(&cnt[dst[e]], 1);
}

__global__ __launch_bounds__(256) void k_dis(const int* __restrict__ cnt, float* __restrict__ dis) {
    int i = blockIdx.x * 256 + threadIdx.x;
    if (i < Nn) dis[i] = rsqrtf((float)cnt[i] + 1.0f);
}

// ---------------- two-level exclusive scan: cnt[40000] -> offs[40001] ----------------
__global__ __launch_bounds__(256)
void k_scan1(const int* __restrict__ cnt, int* __restrict__ offs, int* __restrict__ partial) {
    __shared__ int sm[256];
    int i = blockIdx.x * 256 + threadIdx.x;
    int v = (i < Nn) ? cnt[i] : 0;
    sm[threadIdx.x] = v;
    __syncthreads();
#pragma unroll
    for (int d = 1; d < 256; d <<= 1) {
        int t = (threadIdx.x >= d) ? sm[threadIdx.x - d] : 0;
        __syncthreads();
        sm[threadIdx.x] += t;
        __syncthreads();
    }
    if (i < Nn) offs[i] = sm[threadIdx.x] - v;
    if (threadIdx.x == 255) partial[blockIdx.x] = sm[255];
}

__global__ __launch_bounds__(256)
void k_scan2(int* __restrict__ partial) {
    __shared__ int sm[256];
    int v = (threadIdx.x < NBLK_N) ? partial[threadIdx.x] : 0;
    sm[threadIdx.x] = v;
    __syncthreads();
#pragma unroll
    for (int d = 1; d < 256; d <<= 1) {
        int t = (threadIdx.x >= d) ? sm[threadIdx.x - d] : 0;
        __syncthreads();
        sm[threadIdx.x] += t;
        __syncthreads();
    }
    if (threadIdx.x < NBLK_N) partial[threadIdx.x] = sm[threadIdx.x] - v;
}

__global__ __launch_bounds__(256)
void k_scan3(int* __restrict__ offs, const int* __restrict__ partial) {
    int i = blockIdx.x * 256 + threadIdx.x;
    if (i < Nn) offs[i] += partial[blockIdx.x];
    if (i == 0) offs[Nn] = Ee;
}

// ---------------- CSR fill: bucket src ids by dst ----------------
__global__ __launch_bounds__(256)
void k_fill(const int* __restrict__ src, const int* __restrict__ dst,
            const int* __restrict__ offs, int* __restrict__ cursor,
            unsigned short* __restrict__ src_sorted) {
    int e = blockIdx.x * 256 + threadIdx.x;
    if (e >= Ee) return;
    int d = dst[e];
    int pos = offs[d] + atomicAdd(&cursor[d], 1);
    src_sorted[pos] = (unsigned short)src[e];
}

// ---------------- fp32 tiled GEMM + row scale: C[M,N] = (A[M,K] @ B[K,N]) * dis[row] ----------------
// 128x128 tile, 256 threads, 8x8 micro-tile as 4 quadrants of 4x4, BK=16.
__global__ __launch_bounds__(256, 3)
void k_gemm128s(const float* __restrict__ A, const float* __restrict__ B,
                const float* __restrict__ dis, float* __restrict__ C,
                int M, int N, int K) {
    __shared__ float As[16][132];   // transposed A tile
    __shared__ float Bs[16][132];
    const int tid = threadIdx.x;
    const int rowBase = blockIdx.x * 128;
    const int colBase = blockIdx.y * 128;

    const int ar  = tid >> 2;            // 0..63
    const int akc = (tid & 3) * 4;       // 0,4,8,12
    const int br = tid >> 5;             // 0..7
    const int bc = (tid & 31) * 4;       // 0..124
    const int ty4 = (tid >> 4) * 4;      // 0..60
    const int tx4 = (tid & 15) * 4;      // 0..60

    float acc[8][8] = {};

    for (int k0 = 0; k0 < K; k0 += 16) {
        int r0 = rowBase + ar;       if (r0 >= M) r0 = M - 1;
        int r1 = rowBase + ar + 64;  if (r1 >= M) r1 = M - 1;
        float4 a0 = *(const float4*)&A[(size_t)r0 * K + k0 + akc];
        float4 a1 = *(const float4*)&A[(size_t)r1 * K + k0 + akc];
        float4 b0 = *(const float4*)&B[(size_t)(k0 + br) * N + colBase + bc];
        float4 b1 = *(const float4*)&B[(size_t)(k0 + br + 8) * N + colBase + bc];
        __syncthreads();
        As[akc + 0][ar] = a0.x; As[akc + 1][ar] = a0.y;
        As[akc + 2][ar] = a0.z; As[akc + 3][ar] = a0.w;
        As[akc + 0][ar + 64] = a1.x; As[akc + 1][ar + 64] = a1.y;
        As[akc + 2][ar + 64] = a1.z; As[akc + 3][ar + 64] = a1.w;
        *(float4*)&Bs[br][bc]     = b0;
        *(float4*)&Bs[br + 8][bc] = b1;
        __syncthreads();
#pragma unroll
        for (int kk = 0; kk < 16; ++kk) {
            float a[8], b[8];
            *(float4*)&a[0] = *(const float4*)&As[kk][ty4];
            *(float4*)&a[4] = *(const float4*)&As[kk][ty4 + 64];
            *(float4*)&b[0] = *(const float4*)&Bs[kk][tx4];
            *(float4*)&b[4] = *(const float4*)&Bs[kk][tx4 + 64];
#pragma unroll
            for (int i = 0; i < 8; ++i)
#pragma unroll
                for (int j = 0; j < 8; ++j)
                    acc[i][j] += a[i] * b[j];
        }
    }
#pragma unroll
    for (int i = 0; i < 8; ++i) {
        int r = rowBase + ((i < 4) ? (ty4 + i) : (ty4 + 64 + (i - 4)));
        if (r < M) {
            float s = dis[r];
            *(float4*)&C[(size_t)r * N + colBase + tx4] =
                make_float4(s * acc[i][0], s * acc[i][1], s * acc[i][2], s * acc[i][3]);
            *(float4*)&C[(size_t)r * N + colBase + tx4 + 64] =
                make_float4(s * acc[i][4], s * acc[i][5], s * acc[i][6], s * acc[i][7]);
        }
    }
}

// ---------------- CSR gather on pre-scaled rows h' = dis[row]*h[row] ----------------
// out[n] = dis[n] * ( sum_{src in N(n)} h'[src] + h'[n] ) + bias  (+ReLU)
// One wave per node, V floats per lane, 4x unrolled independent row loads.
template <int HH, bool RELU>
__global__ __launch_bounds__(256)
void k_gather3(const int* __restrict__ offs, const unsigned short* __restrict__ srcs,
               const float* __restrict__ dis, const float* __restrict__ hp,
               const float* __restrict__ bias, float* __restrict__ out) {
    constexpr int V = HH / 64;   // 4 (H=256) or 2 (H=128)
    int n = blockIdx.x * 4 + (threadIdx.x >> 6);
    if (n >= Nn) return;
    int lane = threadIdx.x & 63;
    int col = lane * V;
    int b = __builtin_amdgcn_readfirstlane(offs[n]);
    int e = __builtin_amdgcn_readfirstlane(offs[n + 1]);

    float acc[V];
    // init with self row h'[n]
    {
        const float* sp = hp + (size_t)n * HH + col;
        if constexpr (V == 4) {
            float4 v = *(const float4*)sp;
            acc[0] = v.x; acc[1] = v.y; acc[2] = v.z; acc[3] = v.w;
        } else {
            float2 v = *(const float2*)sp;
            acc[0] = v.x; acc[1] = v.y;
        }
    }

    int i = b;
    for (; i + 4 <= e; i += 4) {
        int s0 = srcs[i], s1 = srcs[i + 1], s2 = srcs[i + 2], s3 = srcs[i + 3];
        const float* p0 = hp + (size_t)s0 * HH + col;
        const float* p1 = hp + (size_t)s1 * HH + col;
        const float* p2 = hp + (size_t)s2 * HH + col;
        const float* p3 = hp + (size_t)s3 * HH + col;
        if constexpr (V == 4) {
            float4 v0 = *(const float4*)p0;
            float4 v1 = *(const float4*)p1;
            float4 v2 = *(const float4*)p2;
            float4 v3 = *(const float4*)p3;
            acc[0] += v0.x + v1.x + v2.x + v3.x;
            acc[1] += v0.y + v1.y + v2.y + v3.y;
            acc[2] += v0.z + v1.z + v2.z + v3.z;
            acc[3] += v0.w + v1.w + v2.w + v3.w;
        } else {
            float2 v0 = *(const float2*)p0;
            float2 v1 = *(const float2*)p1;
            float2 v2 = *(const float2*)p2;
            float2 v3 = *(const float2*)p3;
            acc[0] += v0.x + v1.x + v2.x + v3.x;
            acc[1] += v0.y + v1.y + v2.y + v3.y;
        }
    }
    for (; i < e; ++i) {
        int s0 = srcs[i];
        const float* p0 = hp + (size_t)s0 * HH + col;
        if constexpr (V == 4) {
            float4 v0 = *(const float4*)p0;
            acc[0] += v0.x; acc[1] += v0.y; acc[2] += v0.z; acc[3] += v0.w;
        } else {
            float2 v0 = *(const float2*)p0;
            acc[0] += v0.x; acc[1] += v0.y;
        }
    }

    float dn = dis[n];
    float* op = out + (size_t)n * HH + col;
    if constexpr (V == 4) {
        float4 bv = *(const float4*)&bias[col];
        float4 r;
        r.x = dn * acc[0] + bv.x;
        r.y = dn * acc[1] + bv.y;
        r.z = dn * acc[2] + bv.z;
        r.w = dn * acc[3] + bv.w;
        if (RELU) {
            r.x = fmaxf(r.x, 0.0f); r.y = fmaxf(r.y, 0.0f);
            r.z = fmaxf(r.z, 0.0f); r.w = fmaxf(r.w, 0.0f);
        }
        *(float4*)op = r;
    } else {
        float2 bv = *(const float2*)&bias[col];
        float2 r;
        r.x = dn * acc[0] + bv.x;
        r.y = dn * acc[1] + bv.y;
        if (RELU) { r.x = fmaxf(r.x, 0.0f); r.y = fmaxf(r.y, 0.0f); }
        *(float2*)op = r;
    }
}

// ---------------- pool phase 1: chunked segment-aware accumulation ----------------
__global__ __launch_bounds__(256)
void k_pool_accum(const float* __restrict__ emb, const int* __restrict__ batch,
                  float* __restrict__ ge_accum) {
    int n0 = blockIdx.x * 64;
    int nend = min(n0 + 64, Nn);
    int sub = threadIdx.x >> 6;
    int col = (threadIdx.x & 63) * 2;
    float ax = 0.0f, ay = 0.0f;
    int cur_g = -1;
    for (int n = n0 + sub; n < nend; n += 4) {
        int g = batch[n];
        if (g != cur_g) {
            if (cur_g >= 0) {
                unsafeAtomicAdd(&ge_accum[cur_g * OUTF + col], ax);
                unsafeAtomicAdd(&ge_accum[cur_g * OUTF + col + 1], ay);
            }
            cur_g = g; ax = 0.0f; ay = 0.0f;
        }
        float2 v = *(const float2*)&emb[(size_t)n * OUTF + col];
        ax += v.x; ay += v.y;
    }
    if (cur_g >= 0) {
        unsafeAtomicAdd(&ge_accum[cur_g * OUTF + col], ax);
        unsafeAtomicAdd(&ge_accum[cur_g * OUTF + col + 1], ay);
    }
}

// ---------------- pool phase 2: divide by segment count ----------------
__global__ __launch_bounds__(256)
void k_pool_div(const float* __restrict__ ge_accum, const int* __restrict__ batch,
                float* __restrict__ ge) {
    int idx = blockIdx.x * 256 + threadIdx.x;
    if (idx >= Gg * OUTF) return;
    int g = idx >> 7;
    int lo = 0, hi = Nn;
    while (lo < hi) { int mid = (lo + hi) >> 1; if (batch[mid] < g) lo = mid + 1; else hi = mid; }
    int start = lo;
    hi = Nn;
    while (lo < hi) { int mid = (lo + hi) >> 1; if (batch[mid] < g + 1) lo = mid + 1; else hi = mid; }
    float cnt = (float)(lo - start);
    ge[idx] = ge_accum[idx] / fmaxf(cnt, 1.0f);
}

// ---------------- logits: ge[64,128] @ W_cls[128,2] + b_cls ----------------
__global__ __launch_bounds__(128)
void k_logits(const float* __restrict__ ge, const float* __restrict__ Wc,
              const float* __restrict__ bc, float* __restrict__ out) {
    int t = threadIdx.x;
    int g = t >> 1, c = t & 1;
    float s = bc[c];
    for (int k = 0; k < 128; ++k) s += ge[g * 128 + k] * Wc[k * 2 + c];
    out[t] = s;
}

extern "C" void kernel_launch(void* const* d_in, const int* in_sizes, int n_in,
                              void* d_out, int out_size, void* d_ws, size_t ws_size,
                              hipStream_t stream) {
    const float* x     = (const float*)d_in[0];
    const int*   ei    = (const int*)d_in[1];
    const int*   batch = (const int*)d_in[2];
    const float* W_in  = (const float*)d_in[3];
    const float* b_in  = (const float*)d_in[4];
    const float* W_mid = (const float*)d_in[5];
    const float* b_mid = (const float*)d_in[6];
    const float* W_out = (const float*)d_in[7];
    const float* b_out = (const float*)d_in[8];
    const float* W_cls = (const float*)d_in[9];
    const float* b_cls = (const float*)d_in[10];

    const int* src = ei;
    const int* dst = ei + Ee;

    // workspace layout (4B units) — 83.7 MB total (proven safe)
    float* ws = (float*)d_ws;
    float* dis     = ws;                           // 0
    int*   cnt     = (int*)(ws + 40000);           // 40000
    int*   offs    = (int*)(ws + 80000);           // 80000..120064
    int*   partial = (int*)(ws + 120064);          // 192
    float* ge_accum = ws + 120256;                 // 8192
    unsigned short* src_sorted = (unsigned short*)(ws + 128448);
    float* bufA = ws + 448448;
    float* bufB = ws + 10688448;

    float* out    = (float*)d_out;
    float* ge_out = out + (size_t)Nn * OUTF;
    float* lg_out = ge_out + Gg * OUTF;

    const int nBlkE = (Ee + 255) / 256;
    const int gRows = (Nn + 127) / 128;            // 313
    const int nBlkG = (Nn + 3) / 4;                // 10000

    // ---- CSR build ----
    hipMemsetAsync(cnt, 0, Nn * sizeof(int), stream);
    k_count<<<nBlkE, 256, 0, stream>>>(dst, cnt);
    k_dis<<<NBLK_N, 256, 0, stream>>>(cnt, dis);
    k_scan1<<<NBLK_N, 256, 0, stream>>>(cnt, offs, partial);
    k_scan2<<<1, 256, 0, stream>>>(partial);
    k_scan3<<<NBLK_N, 256, 0, stream>>>(offs, partial);
    hipMemsetAsync(cnt, 0, Nn * sizeof(int), stream);
    k_fill<<<nBlkE, 256, 0, stream>>>(src, dst, offs, cnt, src_sorted);

    // ---- layer 1 ----  bufA = dis * (x @ W_in)   (pre-scaled rows h')
    k_gemm128s<<<dim3(gRows, Hh / 128), 256, 0, stream>>>(x, W_in, dis, bufA, Nn, Hh, INF);
    k_gather3<Hh, true><<<nBlkG, 256, 0, stream>>>(offs, src_sorted, dis, bufA, b_in, bufB);

    // ---- layer 2 ----
    k_gemm128s<<<dim3(gRows, Hh / 128), 256, 0, stream>>>(bufB, W_mid, dis, bufA, Nn, Hh, Hh);
    k_gather3<Hh, true><<<nBlkG, 256, 0, stream>>>(offs, src_sorted, dis, bufA, b_mid, bufB);

    // ---- layer 3 -> node embeddings in d_out ----
    k_gemm128s<<<dim3(gRows, OUTF / 128), 256, 0, stream>>>(bufB, W_out, dis, bufA, Nn, OUTF, Hh);
    k_gather3<OUTF, false><<<nBlkG, 256, 0, stream>>>(offs, src_sorted, dis, bufA, b_out, out);

    // ---- pooling + classifier ----
    hipMemsetAsync(ge_accum, 0, Gg * OUTF * sizeof(float), stream);
    k_pool_accum<<<(Nn + 63) / 64, 256, 0, stream>>>(out, batch, ge_accum);
    k_pool_div<<<(Gg * OUTF + 255) / 256, 256, 0, stream>>>(ge_accum, batch, ge_out);
    k_logits<<<1, 128, 0, stream>>>(ge_out, W_cls, b_cls, lg_out);
}